// Round 12
// baseline (94.396 us; speedup 1.0000x reference)
//
#include <hip/hip_runtime.h>
#include <math.h>

typedef __attribute__((ext_vector_type(8))) short bf16x8;
typedef __attribute__((ext_vector_type(4))) float f32x4;
typedef unsigned short u16;

__device__ __forceinline__ unsigned short f2bf(float f) {
    unsigned u = __builtin_bit_cast(unsigned, f);
    u += 0x7fffu + ((u >> 16) & 1u);          // round-to-nearest-even
    return (unsigned short)(u >> 16);
}

// ---------------------------------------------------------------------------
// Prep 1: sin/cos table for all MZIs of all 3 meshes (+ pack P4 from W).
// ---------------------------------------------------------------------------
__global__ __launch_bounds__(128) void prep_trig_kernel(
    const float* __restrict__ mzi1, const float* __restrict__ mzi2,
    const float* __restrict__ mzi3, const float* __restrict__ W,
    float4* __restrict__ trig, u16* __restrict__ P4)
{
    const int b = blockIdx.x, t = threadIdx.x;
    if (b < 384) {
        if (t >= 64) return;
        const int s = b >> 7, L = b & 127;
        const float* mzi = (s == 0) ? mzi1 : ((s == 1) ? mzi2 : mzi3);
        const int start = L & 1;
        const int m = (128 - start) >> 1;
        float4 v = make_float4(1.f, 0.f, 1.f, 0.f);
        if (t < m) {
            const int off = (L >> 1) * 254 + start * 128 + 2 * t;
            float th = mzi[off], ph = mzi[off + 1];
            float st, ct, sp, cp;
            __sincosf(th, &st, &ct);
            __sincosf(ph, &sp, &cp);
            v = make_float4(ct, st, cp, sp);
        }
        trig[b * 64 + t] = v;
    } else {
        const int n = b - 384;           // output col 0..127
        const int j = t;                  // complex feature 0..127
        const int rre = ((j >> 4) * 32) + (j & 15);
        P4[n * 256 + rre]      = f2bf(W[n * 256 + j]);
        P4[n * 256 + rre + 16] = f2bf(W[n * 256 + j + 128]);
    }
}

// ---------------------------------------------------------------------------
// Prep 2: build row r of mesh s via register+shuffle layer composition,
// then pack to bf16 weight matrices in the block-16 interleaved real form.
// ---------------------------------------------------------------------------
__global__ __launch_bounds__(64) void build_pack_kernel(
    const float* __restrict__ inph,
    const float* __restrict__ outph1, const float* __restrict__ outph2,
    const float* __restrict__ outph3,
    const float4* __restrict__ trig,
    u16* __restrict__ P1, u16* __restrict__ P2, u16* __restrict__ P3)
{
    const int s = blockIdx.x >> 7, r = blockIdx.x & 127, t = threadIdx.x;
    const float4* tg = trig + s * 128 * 64;

    float2 a = make_float2(0.f, 0.f), b2 = make_float2(0.f, 0.f);
    if (s == 0) {
        float sp, cp; __sincosf(inph[r], &sp, &cp);
        if (2 * t == r)     a  = make_float2(cp, sp);
        if (2 * t + 1 == r) b2 = make_float2(cp, sp);
    } else {
        if (2 * t == r)     a.x  = 1.f;
        if (2 * t + 1 == r) b2.x = 1.f;
    }

    float4 tv[4];
    #pragma unroll
    for (int i = 0; i < 4; ++i) tv[i] = tg[i * 64 + t];

    #pragma unroll 4
    for (int L = 0; L < 128; ++L) {
        const float4 c = tv[L & 3];
        if (L < 124) tv[L & 3] = tg[(L + 4) * 64 + t];
        if ((L & 1) == 0) {
            float pr = c.x * (a.x * c.z - a.y * c.w) + c.y * b2.x;
            float pi = c.x * (a.x * c.w + a.y * c.z) + c.y * b2.y;
            float qr = c.y * a.x - c.x * (b2.x * c.z + b2.y * c.w);
            float qi = c.y * a.y - c.x * (b2.y * c.z - b2.x * c.w);
            a = make_float2(pr, pi); b2 = make_float2(qr, qi);
        } else {
            float2 an;
            an.x = __shfl_down(a.x, 1); an.y = __shfl_down(a.y, 1);
            float pr = c.x * (b2.x * c.z - b2.y * c.w) + c.y * an.x;
            float pi = c.x * (b2.x * c.w + b2.y * c.z) + c.y * an.y;
            float qr = c.y * b2.x - c.x * (an.x * c.z + an.y * c.w);
            float qi = c.y * b2.y - c.x * (an.y * c.z - an.x * c.w);
            if (t < 63) b2 = make_float2(pr, pi);
            float2 qs;
            qs.x = __shfl_up(qr, 1); qs.y = __shfl_up(qi, 1);
            if (t >= 1) a = qs;
        }
    }

    const float* outph = (s == 0) ? outph1 : ((s == 1) ? outph2 : outph3);
    #pragma unroll
    for (int h = 0; h < 2; ++h) {
        const int j = 2 * t + h;
        float2 w = h ? b2 : a;
        float sp, cp; __sincosf(outph[j], &sp, &cp);
        const float wr = w.x * cp - w.y * sp;
        const float wi = w.x * sp + w.y * cp;
        const int cre = ((j >> 4) * 32) + (j & 15);
        if (s == 0) {
            P1[cre * 128 + r]        = f2bf(wr);
            P1[(cre + 16) * 128 + r] = f2bf(wi);
        } else {
            u16* P = (s == 1) ? P2 : P3;
            const int rre = ((r >> 4) * 32) + (r & 15);
            P[cre * 256 + rre]             = f2bf(wr);
            P[cre * 256 + rre + 16]        = f2bf(-wi);
            P[(cre + 16) * 256 + rre]      = f2bf(wi);
            P[(cre + 16) * 256 + rre + 16] = f2bf(wr);
        }
    }
}

// ---------------------------------------------------------------------------
// Main fused kernel. R12: 512 threads = 8 NARROW waves (1M x 8N), 64 batch
// rows/block, wave tile 64x32 (mt=4, nt=2). acc = 32 regs (was 64 at 64x64):
// peak live ~ acc32 + Bv32 + A16 + misc ~110 < 128 -> fits the
// __launch_bounds__(512,4) budget spill-free where R7/R10 could not.
// 2 blocks/CU x 8 waves = 4 waves/SIMD (2x R9/R11) to decorrelate the
// barrier-locked latency stalls that held MfmaUtil at 10%.
// No B duplication: each wave owns distinct 32 N-cols. zA 32KB, 2x = 64KB/CU.
// Numerics identical to R9/R11 (f2bf + IEEE div + __expf).
// ---------------------------------------------------------------------------
__global__ __launch_bounds__(512, 4) void ficonn_mfma_kernel(
    const float* __restrict__ x,
    const u16* __restrict__ P1, const u16* __restrict__ P2,
    const u16* __restrict__ P3, const u16* __restrict__ P4,
    const float* __restrict__ al1, const float* __restrict__ be1,
    const float* __restrict__ al2, const float* __restrict__ be2,
    const float* __restrict__ bias, float* __restrict__ out)
{
    __shared__ __align__(16) char zA[32768];   // [64 rows][256 cols] bf16, swizzled

    const int tid  = threadIdx.x;
    const int lane = tid & 63;
    const int wv   = tid >> 6;        // 0..7 (N-split)
    const int l16  = lane & 15;
    const int kg   = lane >> 4;
    const int nb   = wv * 32;         // col base, stages 1-3
    const size_t rowBase = (size_t)blockIdx.x * 64;

    const int jf = wv * 16 + l16;     // this thread's complex feature
    const float av1 = 0.5f * fminf(fmaxf(al1[jf], 0.f), 10.f);
    const float bv1 = fminf(fmaxf(be1[jf], 0.f), 10.f);
    const float av2 = 0.5f * fminf(fmaxf(al2[jf], 0.f), 10.f);
    const float bv2 = fminf(fmaxf(be2[jf], 0.f), 10.f);

    // ---- stage x tile (64 rows x 128 cols fp32) into zA as bf16, coalesced --
    {
        const float4* xg = (const float4*)(x + rowBase * 128);
        #pragma unroll
        for (int i = 0; i < 4; ++i) {
            const int idx = tid + i * 512;        // 0..2047
            const int row = idx >> 5;             // 32 float4 per row
            const int c4  = idx & 31;
            float4 f = xg[idx];
            uint2 v;
            v.x = (unsigned)f2bf(f.x) | ((unsigned)f2bf(f.y) << 16);
            v.y = (unsigned)f2bf(f.z) | ((unsigned)f2bf(f.w) << 16);
            const unsigned byte = ((unsigned)(row * 512 + c4 * 8)) ^ ((unsigned)(row & 31) << 4);
            *(uint2*)(zA + byte) = v;
        }
    }
    __syncthreads();

    f32x4 acc[4][2];

    // ================= stage 1: A = zA (x bf16), B = P1, K=128 ==============
    #pragma unroll
    for (int mt = 0; mt < 4; ++mt)
        #pragma unroll
        for (int nt = 0; nt < 2; ++nt) acc[mt][nt] = (f32x4){0.f, 0.f, 0.f, 0.f};

    {
        bf16x8 Bv[8];    // whole K=128 stage
        #pragma unroll
        for (int ksl = 0; ksl < 4; ++ksl)
            #pragma unroll
            for (int nt = 0; nt < 2; ++nt)
                Bv[ksl * 2 + nt] = *(const bf16x8*)&P1[(nb + nt * 16 + l16) * 128 + ksl * 32 + kg * 8];

        #pragma unroll
        for (int ksl = 0; ksl < 4; ++ksl) {
            const int k0 = ksl * 32 + kg * 8;
            bf16x8 A[4];
            #pragma unroll
            for (int mt = 0; mt < 4; ++mt) {
                const int row = mt * 16 + l16;
                const unsigned byte = ((unsigned)(row * 512 + k0 * 2)) ^ ((unsigned)(row & 31) << 4);
                A[mt] = *(const bf16x8*)(zA + byte);
            }
            #pragma unroll
            for (int nt = 0; nt < 2; ++nt)
                #pragma unroll
                for (int mt = 0; mt < 4; ++mt)
                    acc[mt][nt] = __builtin_amdgcn_mfma_f32_16x16x32_bf16(A[mt], Bv[ksl * 2 + nt], acc[mt][nt], 0, 0, 0);
        }
    }
    __syncthreads();   // all x reads done before overwrite

    // nofu1 + store to zA (wave covers cols [nb, nb+32): Re | Im of feature jf)
    #pragma unroll
    for (int mt = 0; mt < 4; ++mt)
        #pragma unroll
        for (int r = 0; r < 4; ++r) {
            float re = acc[mt][0][r], im = acc[mt][1][r];
            float I = fmaf(re, re, fmaf(im, im, 1e-8f));
            float fct = __expf(-av1 / fmaf(bv1, I, 1.f));
            re *= fct; im *= fct;
            const int row = mt * 16 + kg * 4 + r;
            const int colRe = nb + l16;
            const unsigned sw = (unsigned)(row & 31) << 4;
            *(u16*)(zA + (((unsigned)(row * 512 + colRe * 2)) ^ sw)) = f2bf(re);
            *(u16*)(zA + (((unsigned)(row * 512 + (colRe + 16) * 2)) ^ sw)) = f2bf(im);
        }
    __syncthreads();

    // ================= stage 2: A = zA, B = P2, K=256 =======================
    #pragma unroll
    for (int mt = 0; mt < 4; ++mt)
        #pragma unroll
        for (int nt = 0; nt < 2; ++nt) acc[mt][nt] = (f32x4){0.f, 0.f, 0.f, 0.f};

    #pragma unroll
    for (int ksb = 0; ksb < 2; ++ksb) {
        bf16x8 Bv[8];
        #pragma unroll
        for (int ksl = 0; ksl < 4; ++ksl)
            #pragma unroll
            for (int nt = 0; nt < 2; ++nt)
                Bv[ksl * 2 + nt] = *(const bf16x8*)&P2[(nb + nt * 16 + l16) * 256 + (ksb * 4 + ksl) * 32 + kg * 8];

        #pragma unroll
        for (int ksl = 0; ksl < 4; ++ksl) {
            const int k0 = (ksb * 4 + ksl) * 32 + kg * 8;
            bf16x8 A[4];
            #pragma unroll
            for (int mt = 0; mt < 4; ++mt) {
                const int row = mt * 16 + l16;
                const unsigned byte = ((unsigned)(row * 512 + k0 * 2)) ^ ((unsigned)(row & 31) << 4);
                A[mt] = *(const bf16x8*)(zA + byte);
            }
            #pragma unroll
            for (int nt = 0; nt < 2; ++nt)
                #pragma unroll
                for (int mt = 0; mt < 4; ++mt)
                    acc[mt][nt] = __builtin_amdgcn_mfma_f32_16x16x32_bf16(A[mt], Bv[ksl * 2 + nt], acc[mt][nt], 0, 0, 0);
        }
    }
    __syncthreads();   // all zA reads done before overwrite

    // nofu2 + store to zA
    #pragma unroll
    for (int mt = 0; mt < 4; ++mt)
        #pragma unroll
        for (int r = 0; r < 4; ++r) {
            float re = acc[mt][0][r], im = acc[mt][1][r];
            float I = fmaf(re, re, fmaf(im, im, 1e-8f));
            float fct = __expf(-av2 / fmaf(bv2, I, 1.f));
            re *= fct; im *= fct;
            const int row = mt * 16 + kg * 4 + r;
            const int colRe = nb + l16;
            const unsigned sw = (unsigned)(row & 31) << 4;
            *(u16*)(zA + (((unsigned)(row * 512 + colRe * 2)) ^ sw)) = f2bf(re);
            *(u16*)(zA + (((unsigned)(row * 512 + (colRe + 16) * 2)) ^ sw)) = f2bf(im);
        }
    __syncthreads();

    // ================= stage 3: A = zA, B = P3, K=256 (no nofu) =============
    #pragma unroll
    for (int mt = 0; mt < 4; ++mt)
        #pragma unroll
        for (int nt = 0; nt < 2; ++nt) acc[mt][nt] = (f32x4){0.f, 0.f, 0.f, 0.f};

    #pragma unroll
    for (int ksb = 0; ksb < 2; ++ksb) {
        bf16x8 Bv[8];
        #pragma unroll
        for (int ksl = 0; ksl < 4; ++ksl)
            #pragma unroll
            for (int nt = 0; nt < 2; ++nt)
                Bv[ksl * 2 + nt] = *(const bf16x8*)&P3[(nb + nt * 16 + l16) * 256 + (ksb * 4 + ksl) * 32 + kg * 8];

        #pragma unroll
        for (int ksl = 0; ksl < 4; ++ksl) {
            const int k0 = (ksb * 4 + ksl) * 32 + kg * 8;
            bf16x8 A[4];
            #pragma unroll
            for (int mt = 0; mt < 4; ++mt) {
                const int row = mt * 16 + l16;
                const unsigned byte = ((unsigned)(row * 512 + k0 * 2)) ^ ((unsigned)(row & 31) << 4);
                A[mt] = *(const bf16x8*)(zA + byte);
            }
            #pragma unroll
            for (int nt = 0; nt < 2; ++nt)
                #pragma unroll
                for (int mt = 0; mt < 4; ++mt)
                    acc[mt][nt] = __builtin_amdgcn_mfma_f32_16x16x32_bf16(A[mt], Bv[ksl * 2 + nt], acc[mt][nt], 0, 0, 0);
        }
    }
    __syncthreads();

    // store z3 (plain) to zA
    #pragma unroll
    for (int mt = 0; mt < 4; ++mt)
        #pragma unroll
        for (int r = 0; r < 4; ++r) {
            const int row = mt * 16 + kg * 4 + r;
            const int colRe = nb + l16;
            const unsigned sw = (unsigned)(row & 31) << 4;
            *(u16*)(zA + (((unsigned)(row * 512 + colRe * 2)) ^ sw)) = f2bf(acc[mt][0][r]);
            *(u16*)(zA + (((unsigned)(row * 512 + (colRe + 16) * 2)) ^ sw)) = f2bf(acc[mt][1][r]);
        }
    __syncthreads();

    // ================= final: A = zA, B = P4 [128 cols][256 k], 16 cols/wave =
    f32x4 facc[4];
    #pragma unroll
    for (int mt = 0; mt < 4; ++mt) facc[mt] = (f32x4){0.f, 0.f, 0.f, 0.f};

    const int nb2 = wv * 16;
    #pragma unroll
    for (int ksb = 0; ksb < 2; ++ksb) {
        bf16x8 Bv[4];
        #pragma unroll
        for (int ksl = 0; ksl < 4; ++ksl)
            Bv[ksl] = *(const bf16x8*)&P4[(nb2 + l16) * 256 + (ksb * 4 + ksl) * 32 + kg * 8];

        #pragma unroll
        for (int ksl = 0; ksl < 4; ++ksl) {
            const int k0 = (ksb * 4 + ksl) * 32 + kg * 8;
            bf16x8 A[4];
            #pragma unroll
            for (int mt = 0; mt < 4; ++mt) {
                const int row = mt * 16 + l16;
                const unsigned byte = ((unsigned)(row * 512 + k0 * 2)) ^ ((unsigned)(row & 31) << 4);
                A[mt] = *(const bf16x8*)(zA + byte);
            }
            #pragma unroll
            for (int mt = 0; mt < 4; ++mt)
                facc[mt] = __builtin_amdgcn_mfma_f32_16x16x32_bf16(A[mt], Bv[ksl], facc[mt], 0, 0, 0);
        }
    }

    const float bcol = bias[nb2 + l16];
    #pragma unroll
    for (int mt = 0; mt < 4; ++mt)
        #pragma unroll
        for (int r = 0; r < 4; ++r) {
            const size_t row = rowBase + mt * 16 + kg * 4 + r;
            out[row * 128 + nb2 + l16] = facc[mt][r] + bcol;
        }
}

extern "C" void kernel_launch(void* const* d_in, const int* in_sizes, int n_in,
                              void* d_out, int out_size, void* d_ws, size_t ws_size,
                              hipStream_t stream)
{
    const float* x      = (const float*)d_in[0];
    const float* inph   = (const float*)d_in[1];
    const float* mzi1   = (const float*)d_in[2];
    const float* outph1 = (const float*)d_in[3];
    const float* alpha1 = (const float*)d_in[4];
    const float* beta1  = (const float*)d_in[5];
    const float* mzi2   = (const float*)d_in[6];
    const float* outph2 = (const float*)d_in[7];
    const float* alpha2 = (const float*)d_in[8];
    const float* beta2  = (const float*)d_in[9];
    const float* mzi3   = (const float*)d_in[10];
    const float* outph3 = (const float*)d_in[11];
    const float* W      = (const float*)d_in[12];
    const float* bias   = (const float*)d_in[13];

    const int B = in_sizes[0] / 128;

    // ws layout
    float4* trig = (float4*)d_ws;                          // 3*128*64*16 = 393216 B
    u16* P1 = (u16*)((char*)d_ws + 393216);                // 65536 B
    u16* P2 = P1 + 32768;                                  // 131072 B
    u16* P3 = P2 + 65536;                                  // 131072 B
    u16* P4 = P3 + 65536;                                  // 65536 B

    prep_trig_kernel<<<512, 128, 0, stream>>>(mzi1, mzi2, mzi3, W, trig, P4);
    build_pack_kernel<<<384, 64, 0, stream>>>(inph, outph1, outph2, outph3, trig, P1, P2, P3);
    ficonn_mfma_kernel<<<B / 64, 512, 0, stream>>>(
        x, P1, P2, P3, P4, alpha1, beta1, alpha2, beta2, bias, (float*)d_out);
}

// Round 13
// 91.968 us; speedup vs baseline: 1.0264x; 1.0264x over previous
//
#include <hip/hip_runtime.h>
#include <math.h>

typedef __attribute__((ext_vector_type(8))) short bf16x8;
typedef __attribute__((ext_vector_type(4))) float f32x4;
typedef unsigned short u16;

__device__ __forceinline__ unsigned short f2bf(float f) {
    unsigned u = __builtin_bit_cast(unsigned, f);
    u += 0x7fffu + ((u >> 16) & 1u);          // round-to-nearest-even
    return (unsigned short)(u >> 16);
}

// ---------------------------------------------------------------------------
// Prep 1: sin/cos table for all MZIs of all 3 meshes (+ pack P4 from W).
// ---------------------------------------------------------------------------
__global__ __launch_bounds__(128) void prep_trig_kernel(
    const float* __restrict__ mzi1, const float* __restrict__ mzi2,
    const float* __restrict__ mzi3, const float* __restrict__ W,
    float4* __restrict__ trig, u16* __restrict__ P4)
{
    const int b = blockIdx.x, t = threadIdx.x;
    if (b < 384) {
        if (t >= 64) return;
        const int s = b >> 7, L = b & 127;
        const float* mzi = (s == 0) ? mzi1 : ((s == 1) ? mzi2 : mzi3);
        const int start = L & 1;
        const int m = (128 - start) >> 1;
        float4 v = make_float4(1.f, 0.f, 1.f, 0.f);
        if (t < m) {
            const int off = (L >> 1) * 254 + start * 128 + 2 * t;
            float th = mzi[off], ph = mzi[off + 1];
            float st, ct, sp, cp;
            __sincosf(th, &st, &ct);
            __sincosf(ph, &sp, &cp);
            v = make_float4(ct, st, cp, sp);
        }
        trig[b * 64 + t] = v;
    } else {
        const int n = b - 384;           // output col 0..127
        const int j = t;                  // complex feature 0..127
        const int rre = ((j >> 4) * 32) + (j & 15);
        P4[n * 256 + rre]      = f2bf(W[n * 256 + j]);
        P4[n * 256 + rre + 16] = f2bf(W[n * 256 + j + 128]);
    }
}

// ---------------------------------------------------------------------------
// Prep 2: build row r of mesh s via register+shuffle layer composition,
// then pack to bf16 weight matrices in the block-16 interleaved real form.
// ---------------------------------------------------------------------------
__global__ __launch_bounds__(64) void build_pack_kernel(
    const float* __restrict__ inph,
    const float* __restrict__ outph1, const float* __restrict__ outph2,
    const float* __restrict__ outph3,
    const float4* __restrict__ trig,
    u16* __restrict__ P1, u16* __restrict__ P2, u16* __restrict__ P3)
{
    const int s = blockIdx.x >> 7, r = blockIdx.x & 127, t = threadIdx.x;
    const float4* tg = trig + s * 128 * 64;

    float2 a = make_float2(0.f, 0.f), b2 = make_float2(0.f, 0.f);
    if (s == 0) {
        float sp, cp; __sincosf(inph[r], &sp, &cp);
        if (2 * t == r)     a  = make_float2(cp, sp);
        if (2 * t + 1 == r) b2 = make_float2(cp, sp);
    } else {
        if (2 * t == r)     a.x  = 1.f;
        if (2 * t + 1 == r) b2.x = 1.f;
    }

    float4 tv[4];
    #pragma unroll
    for (int i = 0; i < 4; ++i) tv[i] = tg[i * 64 + t];

    #pragma unroll 4
    for (int L = 0; L < 128; ++L) {
        const float4 c = tv[L & 3];
        if (L < 124) tv[L & 3] = tg[(L + 4) * 64 + t];
        if ((L & 1) == 0) {
            float pr = c.x * (a.x * c.z - a.y * c.w) + c.y * b2.x;
            float pi = c.x * (a.x * c.w + a.y * c.z) + c.y * b2.y;
            float qr = c.y * a.x - c.x * (b2.x * c.z + b2.y * c.w);
            float qi = c.y * a.y - c.x * (b2.y * c.z - b2.x * c.w);
            a = make_float2(pr, pi); b2 = make_float2(qr, qi);
        } else {
            float2 an;
            an.x = __shfl_down(a.x, 1); an.y = __shfl_down(a.y, 1);
            float pr = c.x * (b2.x * c.z - b2.y * c.w) + c.y * an.x;
            float pi = c.x * (b2.x * c.w + b2.y * c.z) + c.y * an.y;
            float qr = c.y * b2.x - c.x * (an.x * c.z + an.y * c.w);
            float qi = c.y * b2.y - c.x * (an.y * c.z - an.x * c.w);
            if (t < 63) b2 = make_float2(pr, pi);
            float2 qs;
            qs.x = __shfl_up(qr, 1); qs.y = __shfl_up(qi, 1);
            if (t >= 1) a = qs;
        }
    }

    const float* outph = (s == 0) ? outph1 : ((s == 1) ? outph2 : outph3);
    #pragma unroll
    for (int h = 0; h < 2; ++h) {
        const int j = 2 * t + h;
        float2 w = h ? b2 : a;
        float sp, cp; __sincosf(outph[j], &sp, &cp);
        const float wr = w.x * cp - w.y * sp;
        const float wi = w.x * sp + w.y * cp;
        const int cre = ((j >> 4) * 32) + (j & 15);
        if (s == 0) {
            P1[cre * 128 + r]        = f2bf(wr);
            P1[(cre + 16) * 128 + r] = f2bf(wi);
        } else {
            u16* P = (s == 1) ? P2 : P3;
            const int rre = ((r >> 4) * 32) + (r & 15);
            P[cre * 256 + rre]             = f2bf(wr);
            P[cre * 256 + rre + 16]        = f2bf(-wi);
            P[(cre + 16) * 256 + rre]      = f2bf(wi);
            P[(cre + 16) * 256 + rre + 16] = f2bf(wr);
        }
    }
}

// ---------------------------------------------------------------------------
// Main fused kernel. R13: R12 structure (512 threads = 8 narrow waves,
// 1M x 8N, wave tile 64x32, 64 rows/block, zA 32KB swizzled) MINUS the
// forced register batches. R12's Bv[8]+A[4]-per-ksb arrays (48 regs of
// forced-live state, a proven-null ILP experiment from R11) busted the
// (512,4) 128-reg budget: 42MB spill writes. Here B-fragments are
// dereferenced inline (compiler hoists within budget); A kept as a 4-frag
// batch (16 regs, each reused 2x). Demand: ~60 arch + 32 acc < 128.
// Numerics identical (f2bf + IEEE div + __expf).
// ---------------------------------------------------------------------------
__global__ __launch_bounds__(512, 4) void ficonn_mfma_kernel(
    const float* __restrict__ x,
    const u16* __restrict__ P1, const u16* __restrict__ P2,
    const u16* __restrict__ P3, const u16* __restrict__ P4,
    const float* __restrict__ al1, const float* __restrict__ be1,
    const float* __restrict__ al2, const float* __restrict__ be2,
    const float* __restrict__ bias, float* __restrict__ out)
{
    __shared__ __align__(16) char zA[32768];   // [64 rows][256 cols] bf16, swizzled

    const int tid  = threadIdx.x;
    const int lane = tid & 63;
    const int wv   = tid >> 6;        // 0..7 (N-split)
    const int l16  = lane & 15;
    const int kg   = lane >> 4;
    const int nb   = wv * 32;         // col base, stages 1-3
    const size_t rowBase = (size_t)blockIdx.x * 64;

    const int jf = wv * 16 + l16;     // this thread's complex feature
    const float av1 = 0.5f * fminf(fmaxf(al1[jf], 0.f), 10.f);
    const float bv1 = fminf(fmaxf(be1[jf], 0.f), 10.f);
    const float av2 = 0.5f * fminf(fmaxf(al2[jf], 0.f), 10.f);
    const float bv2 = fminf(fmaxf(be2[jf], 0.f), 10.f);

    // ---- stage x tile (64 rows x 128 cols fp32) into zA as bf16, coalesced --
    {
        const float4* xg = (const float4*)(x + rowBase * 128);
        #pragma unroll
        for (int i = 0; i < 4; ++i) {
            const int idx = tid + i * 512;        // 0..2047
            const int row = idx >> 5;             // 32 float4 per row
            const int c4  = idx & 31;
            float4 f = xg[idx];
            uint2 v;
            v.x = (unsigned)f2bf(f.x) | ((unsigned)f2bf(f.y) << 16);
            v.y = (unsigned)f2bf(f.z) | ((unsigned)f2bf(f.w) << 16);
            const unsigned byte = ((unsigned)(row * 512 + c4 * 8)) ^ ((unsigned)(row & 31) << 4);
            *(uint2*)(zA + byte) = v;
        }
    }
    __syncthreads();

    f32x4 acc[4][2];

    // ================= stage 1: A = zA (x bf16), B = P1, K=128 ==============
    #pragma unroll
    for (int mt = 0; mt < 4; ++mt)
        #pragma unroll
        for (int nt = 0; nt < 2; ++nt) acc[mt][nt] = (f32x4){0.f, 0.f, 0.f, 0.f};

    #pragma unroll
    for (int ksl = 0; ksl < 4; ++ksl) {
        const int k0 = ksl * 32 + kg * 8;
        bf16x8 A[4];
        #pragma unroll
        for (int mt = 0; mt < 4; ++mt) {
            const int row = mt * 16 + l16;
            const unsigned byte = ((unsigned)(row * 512 + k0 * 2)) ^ ((unsigned)(row & 31) << 4);
            A[mt] = *(const bf16x8*)(zA + byte);
        }
        #pragma unroll
        for (int nt = 0; nt < 2; ++nt) {
            bf16x8 Bf = *(const bf16x8*)&P1[(nb + nt * 16 + l16) * 128 + k0];
            #pragma unroll
            for (int mt = 0; mt < 4; ++mt)
                acc[mt][nt] = __builtin_amdgcn_mfma_f32_16x16x32_bf16(A[mt], Bf, acc[mt][nt], 0, 0, 0);
        }
    }
    __syncthreads();   // all x reads done before overwrite

    // nofu1 + store to zA (wave covers cols [nb, nb+32): Re | Im of feature jf)
    #pragma unroll
    for (int mt = 0; mt < 4; ++mt)
        #pragma unroll
        for (int r = 0; r < 4; ++r) {
            float re = acc[mt][0][r], im = acc[mt][1][r];
            float I = fmaf(re, re, fmaf(im, im, 1e-8f));
            float fct = __expf(-av1 / fmaf(bv1, I, 1.f));
            re *= fct; im *= fct;
            const int row = mt * 16 + kg * 4 + r;
            const int colRe = nb + l16;
            const unsigned sw = (unsigned)(row & 31) << 4;
            *(u16*)(zA + (((unsigned)(row * 512 + colRe * 2)) ^ sw)) = f2bf(re);
            *(u16*)(zA + (((unsigned)(row * 512 + (colRe + 16) * 2)) ^ sw)) = f2bf(im);
        }
    __syncthreads();

    // ================= stage 2: A = zA, B = P2, K=256 =======================
    #pragma unroll
    for (int mt = 0; mt < 4; ++mt)
        #pragma unroll
        for (int nt = 0; nt < 2; ++nt) acc[mt][nt] = (f32x4){0.f, 0.f, 0.f, 0.f};

    #pragma unroll
    for (int ks = 0; ks < 8; ++ks) {
        const int k0 = ks * 32 + kg * 8;
        bf16x8 A[4];
        #pragma unroll
        for (int mt = 0; mt < 4; ++mt) {
            const int row = mt * 16 + l16;
            const unsigned byte = ((unsigned)(row * 512 + k0 * 2)) ^ ((unsigned)(row & 31) << 4);
            A[mt] = *(const bf16x8*)(zA + byte);
        }
        #pragma unroll
        for (int nt = 0; nt < 2; ++nt) {
            bf16x8 Bf = *(const bf16x8*)&P2[(nb + nt * 16 + l16) * 256 + k0];
            #pragma unroll
            for (int mt = 0; mt < 4; ++mt)
                acc[mt][nt] = __builtin_amdgcn_mfma_f32_16x16x32_bf16(A[mt], Bf, acc[mt][nt], 0, 0, 0);
        }
    }
    __syncthreads();   // all zA reads done before overwrite

    // nofu2 + store to zA
    #pragma unroll
    for (int mt = 0; mt < 4; ++mt)
        #pragma unroll
        for (int r = 0; r < 4; ++r) {
            float re = acc[mt][0][r], im = acc[mt][1][r];
            float I = fmaf(re, re, fmaf(im, im, 1e-8f));
            float fct = __expf(-av2 / fmaf(bv2, I, 1.f));
            re *= fct; im *= fct;
            const int row = mt * 16 + kg * 4 + r;
            const int colRe = nb + l16;
            const unsigned sw = (unsigned)(row & 31) << 4;
            *(u16*)(zA + (((unsigned)(row * 512 + colRe * 2)) ^ sw)) = f2bf(re);
            *(u16*)(zA + (((unsigned)(row * 512 + (colRe + 16) * 2)) ^ sw)) = f2bf(im);
        }
    __syncthreads();

    // ================= stage 3: A = zA, B = P3, K=256 (no nofu) =============
    #pragma unroll
    for (int mt = 0; mt < 4; ++mt)
        #pragma unroll
        for (int nt = 0; nt < 2; ++nt) acc[mt][nt] = (f32x4){0.f, 0.f, 0.f, 0.f};

    #pragma unroll
    for (int ks = 0; ks < 8; ++ks) {
        const int k0 = ks * 32 + kg * 8;
        bf16x8 A[4];
        #pragma unroll
        for (int mt = 0; mt < 4; ++mt) {
            const int row = mt * 16 + l16;
            const unsigned byte = ((unsigned)(row * 512 + k0 * 2)) ^ ((unsigned)(row & 31) << 4);
            A[mt] = *(const bf16x8*)(zA + byte);
        }
        #pragma unroll
        for (int nt = 0; nt < 2; ++nt) {
            bf16x8 Bf = *(const bf16x8*)&P3[(nb + nt * 16 + l16) * 256 + k0];
            #pragma unroll
            for (int mt = 0; mt < 4; ++mt)
                acc[mt][nt] = __builtin_amdgcn_mfma_f32_16x16x32_bf16(A[mt], Bf, acc[mt][nt], 0, 0, 0);
        }
    }
    __syncthreads();

    // store z3 (plain) to zA
    #pragma unroll
    for (int mt = 0; mt < 4; ++mt)
        #pragma unroll
        for (int r = 0; r < 4; ++r) {
            const int row = mt * 16 + kg * 4 + r;
            const int colRe = nb + l16;
            const unsigned sw = (unsigned)(row & 31) << 4;
            *(u16*)(zA + (((unsigned)(row * 512 + colRe * 2)) ^ sw)) = f2bf(acc[mt][0][r]);
            *(u16*)(zA + (((unsigned)(row * 512 + (colRe + 16) * 2)) ^ sw)) = f2bf(acc[mt][1][r]);
        }
    __syncthreads();

    // ================= final: A = zA, B = P4 [128 cols][256 k], 16 cols/wave =
    f32x4 facc[4];
    #pragma unroll
    for (int mt = 0; mt < 4; ++mt) facc[mt] = (f32x4){0.f, 0.f, 0.f, 0.f};

    const int nb2 = wv * 16;
    #pragma unroll
    for (int ks = 0; ks < 8; ++ks) {
        const int k0 = ks * 32 + kg * 8;
        bf16x8 A[4];
        #pragma unroll
        for (int mt = 0; mt < 4; ++mt) {
            const int row = mt * 16 + l16;
            const unsigned byte = ((unsigned)(row * 512 + k0 * 2)) ^ ((unsigned)(row & 31) << 4);
            A[mt] = *(const bf16x8*)(zA + byte);
        }
        bf16x8 Bf = *(const bf16x8*)&P4[(nb2 + l16) * 256 + k0];
        #pragma unroll
        for (int mt = 0; mt < 4; ++mt)
            facc[mt] = __builtin_amdgcn_mfma_f32_16x16x32_bf16(A[mt], Bf, facc[mt], 0, 0, 0);
    }

    const float bcol = bias[nb2 + l16];
    #pragma unroll
    for (int mt = 0; mt < 4; ++mt)
        #pragma unroll
        for (int r = 0; r < 4; ++r) {
            const size_t row = rowBase + mt * 16 + kg * 4 + r;
            out[row * 128 + nb2 + l16] = facc[mt][r] + bcol;
        }
}

extern "C" void kernel_launch(void* const* d_in, const int* in_sizes, int n_in,
                              void* d_out, int out_size, void* d_ws, size_t ws_size,
                              hipStream_t stream)
{
    const float* x      = (const float*)d_in[0];
    const float* inph   = (const float*)d_in[1];
    const float* mzi1   = (const float*)d_in[2];
    const float* outph1 = (const float*)d_in[3];
    const float* alpha1 = (const float*)d_in[4];
    const float* beta1  = (const float*)d_in[5];
    const float* mzi2   = (const float*)d_in[6];
    const float* outph2 = (const float*)d_in[7];
    const float* alpha2 = (const float*)d_in[8];
    const float* beta2  = (const float*)d_in[9];
    const float* mzi3   = (const float*)d_in[10];
    const float* outph3 = (const float*)d_in[11];
    const float* W      = (const float*)d_in[12];
    const float* bias   = (const float*)d_in[13];

    const int B = in_sizes[0] / 128;

    // ws layout
    float4* trig = (float4*)d_ws;                          // 3*128*64*16 = 393216 B
    u16* P1 = (u16*)((char*)d_ws + 393216);                // 65536 B
    u16* P2 = P1 + 32768;                                  // 131072 B
    u16* P3 = P2 + 65536;                                  // 131072 B
    u16* P4 = P3 + 65536;                                  // 65536 B

    prep_trig_kernel<<<512, 128, 0, stream>>>(mzi1, mzi2, mzi3, W, trig, P4);
    build_pack_kernel<<<384, 64, 0, stream>>>(inph, outph1, outph2, outph3, trig, P1, P2, P3);
    ficonn_mfma_kernel<<<B / 64, 512, 0, stream>>>(
        x, P1, P2, P3, P4, alpha1, beta1, alpha2, beta2, bias, (float*)d_out);
}